// Round 1
// baseline (2679.826 us; speedup 1.0000x reference)
//
#include <hip/hip_runtime.h>
#include <math.h>

#define N_NODES 100000
#define N_GRAPHS 512
#define EMB 64

// ---------------- utility ----------------
__global__ void k_zero(float* __restrict__ p, int n) {
    int i = blockIdx.x * blockDim.x + threadIdx.x;
    int stride = gridDim.x * blockDim.x;
    for (; i < n; i += stride) p[i] = 0.0f;
}

// count in-degree of dst (float atomic, exact for counts < 2^24)
__global__ void k_count(const int* __restrict__ dst, int E, float* __restrict__ deg) {
    int i = blockIdx.x * blockDim.x + threadIdx.x;
    int stride = gridDim.x * blockDim.x;
    for (; i < E; i += stride) atomicAdd(&deg[dst[i]], 1.0f);
}

// deg -> rsqrt(deg + 1)  (self-loop contributes 1; always > 0)
__global__ void k_dsq(float* __restrict__ deg, int n) {
    int i = blockIdx.x * blockDim.x + threadIdx.x;
    int stride = gridDim.x * blockDim.x;
    for (; i < n; i += stride) deg[i] = rsqrtf(deg[i] + 1.0f);
}

// agg[n][c] = dsq[n]^2 * hin[n][c]   (self-loop message; also zero-inits agg)
template <int D>
__global__ void k_selfinit(const float* __restrict__ hin, const float* __restrict__ dsq,
                           float* __restrict__ agg) {
    int i = blockIdx.x * blockDim.x + threadIdx.x;
    int stride = gridDim.x * blockDim.x;
    const int total = N_NODES * D;
    for (; i < total; i += stride) {
        int n = i / D;
        float w = dsq[n];
        agg[i] = w * w * hin[i];
    }
}

// scatter-add edge messages: agg[dst][c] += dsq[src]*dsq[dst]*hin[src][c]
// LPE lanes cooperate per edge (lane = channel)
template <int D, int LPE>
__global__ void k_edges(const int* __restrict__ src, const int* __restrict__ dst, int E,
                        const float* __restrict__ dsq, const float* __restrict__ hin,
                        float* __restrict__ agg) {
    long long gt = (long long)blockIdx.x * blockDim.x + threadIdx.x;
    int lane = (int)(gt % LPE);
    long long e = gt / LPE;
    long long estride = ((long long)gridDim.x * blockDim.x) / LPE;
    for (; e < E; e += estride) {
        int s = src[e];
        int d = dst[e];
        float w = dsq[s] * dsq[d];
        if (LPE == D || lane < D) {
            atomicAdd(&agg[d * D + lane], w * hin[s * D + lane]);
        }
    }
}

// hout[n][o] = act( sum_k agg[n][k] * W[k][o] + b[o] )
// ACT: 0 = leaky_relu(0.01), 1 = relu
template <int DIN, int ACT>
__global__ void k_mm(const float* __restrict__ agg, const float* __restrict__ W,
                     const float* __restrict__ b, float* __restrict__ hout) {
    __shared__ float Wl[DIN * EMB];
    for (int i = threadIdx.x; i < DIN * EMB; i += blockDim.x) Wl[i] = W[i];
    __syncthreads();
    int gt = blockIdx.x * blockDim.x + threadIdx.x;
    const int total = N_NODES * EMB;
    int stride = gridDim.x * blockDim.x;
    for (; gt < total; gt += stride) {
        int n = gt >> 6;
        int o = gt & 63;
        const float* arow = agg + n * DIN;
        float s = b[o];
#pragma unroll
        for (int k = 0; k < DIN; ++k) s += arow[k] * Wl[k * EMB + o];
        if (ACT) {
            hout[gt] = fmaxf(s, 0.0f);
        } else {
            hout[gt] = (s > 0.0f) ? s : 0.01f * s;
        }
    }
}

// segmented mean-pool numerator/denominator using sorted batch_index
// block = 1 wave (64 threads), handles CHUNK consecutive nodes
__global__ void k_pool(const float* __restrict__ h, const int* __restrict__ batch,
                       float* __restrict__ psum, float* __restrict__ pcnt) {
    const int CHUNK = 256;
    int lane = threadIdx.x;
    int start = blockIdx.x * CHUNK;
    if (start >= N_NODES) return;
    int end = start + CHUNK;
    if (end > N_NODES) end = N_NODES;

    int curg = batch[start];
    float acc = 0.0f;
    int cnt = 0;
    for (int n = start; n < end; ++n) {
        int g = batch[n];
        if (g != curg) {
            atomicAdd(&psum[curg * EMB + lane], acc);
            if (lane == 0) atomicAdd(&pcnt[curg], (float)cnt);
            acc = 0.0f;
            cnt = 0;
            curg = g;
        }
        acc += h[n * EMB + lane];
        ++cnt;
    }
    atomicAdd(&psum[curg * EMB + lane], acc);
    if (lane == 0) atomicAdd(&pcnt[curg], (float)cnt);
}

// out[g] = sigmoid( (sum_c psum[g][c]*Wfc[c]) / max(cnt,1) + bfc )
__global__ void k_fc(const float* __restrict__ psum, const float* __restrict__ pcnt,
                     const float* __restrict__ Wfc, const float* __restrict__ bfc,
                     float* __restrict__ out) {
    int g = blockIdx.x;
    int lane = threadIdx.x;  // 64 threads
    float v = psum[g * EMB + lane] * Wfc[lane];
#pragma unroll
    for (int off = 32; off; off >>= 1) v += __shfl_down(v, off, 64);
    if (lane == 0) {
        float c = fmaxf(pcnt[g], 1.0f);
        float z = v / c + bfc[0];
        out[g] = 1.0f / (1.0f + expf(-z));
    }
}

extern "C" void kernel_launch(void* const* d_in, const int* in_sizes, int n_in,
                              void* d_out, int out_size, void* d_ws, size_t ws_size,
                              hipStream_t stream) {
    const float* x        = (const float*)d_in[0];
    const int*   edge     = (const int*)d_in[1];
    const int*   batch    = (const int*)d_in[2];
    const float* W0 = (const float*)d_in[3];
    const float* b0 = (const float*)d_in[4];
    const float* W1 = (const float*)d_in[5];
    const float* b1 = (const float*)d_in[6];
    const float* W2 = (const float*)d_in[7];
    const float* b2 = (const float*)d_in[8];
    const float* W3 = (const float*)d_in[9];
    const float* b3 = (const float*)d_in[10];
    const float* Wfc = (const float*)d_in[11];
    const float* bfc = (const float*)d_in[12];
    float* out = (float*)d_out;

    const int E = in_sizes[1] / 2;
    const int* src = edge;
    const int* dst = edge + E;

    // workspace layout (floats)
    float* ws   = (float*)d_ws;
    float* dsq  = ws;                        // N_NODES
    float* bufA = dsq + N_NODES;             // N_NODES * 64
    float* bufB = bufA + N_NODES * EMB;      // N_NODES * 64
    float* psum = bufB + N_NODES * EMB;      // N_GRAPHS * 64
    float* pcnt = psum + N_GRAPHS * EMB;     // N_GRAPHS

    // degree -> dsq
    k_zero<<<256, 256, 0, stream>>>(dsq, N_NODES);
    k_count<<<2048, 256, 0, stream>>>(dst, E, dsq);
    k_dsq<<<256, 256, 0, stream>>>(dsq, N_NODES);

    // layer 0: aggregate x (12-dim) then matmul W0 (12x64), leaky_relu
    k_selfinit<12><<<2048, 256, 0, stream>>>(x, dsq, bufB);
    k_edges<12, 16><<<4096, 256, 0, stream>>>(src, dst, E, dsq, x, bufB);
    k_mm<12, 0><<<4096, 256, 0, stream>>>(bufB, W0, b0, bufA);

    // layer 1
    k_selfinit<64><<<2048, 256, 0, stream>>>(bufA, dsq, bufB);
    k_edges<64, 64><<<4096, 256, 0, stream>>>(src, dst, E, dsq, bufA, bufB);
    k_mm<64, 0><<<4096, 256, 0, stream>>>(bufB, W1, b1, bufA);

    // layer 2
    k_selfinit<64><<<2048, 256, 0, stream>>>(bufA, dsq, bufB);
    k_edges<64, 64><<<4096, 256, 0, stream>>>(src, dst, E, dsq, bufA, bufB);
    k_mm<64, 0><<<4096, 256, 0, stream>>>(bufB, W2, b2, bufA);

    // layer 3 (relu)
    k_selfinit<64><<<2048, 256, 0, stream>>>(bufA, dsq, bufB);
    k_edges<64, 64><<<4096, 256, 0, stream>>>(src, dst, E, dsq, bufA, bufB);
    k_mm<64, 1><<<4096, 256, 0, stream>>>(bufB, W3, b3, bufA);

    // mean pool + fc + sigmoid
    k_zero<<<64, 256, 0, stream>>>(psum, N_GRAPHS * EMB + N_GRAPHS);
    k_pool<<<(N_NODES + 255) / 256, 64, 0, stream>>>(bufA, batch, psum, pcnt);
    k_fc<<<N_GRAPHS, 64, 0, stream>>>(psum, pcnt, Wfc, bfc, out);
}

// Round 2
// 1197.978 us; speedup vs baseline: 2.2370x; 2.2370x over previous
//
#include <hip/hip_runtime.h>
#include <math.h>

#define N_NODES 100000
#define N_GRAPHS 512
#define EMB 64
#define SCAN_B 1024

// ---------------- utility ----------------
__global__ void k_zero_f(float* __restrict__ p, int n) {
    int i = blockIdx.x * blockDim.x + threadIdx.x;
    int stride = gridDim.x * blockDim.x;
    for (; i < n; i += stride) p[i] = 0.0f;
}
__global__ void k_zero_i(int* __restrict__ p, int n) {
    int i = blockIdx.x * blockDim.x + threadIdx.x;
    int stride = gridDim.x * blockDim.x;
    for (; i < n; i += stride) p[i] = 0;
}

// in-degree histogram (int atomics)
__global__ void k_hist(const int* __restrict__ dst, int E, int* __restrict__ cnt) {
    int i = blockIdx.x * blockDim.x + threadIdx.x;
    int stride = gridDim.x * blockDim.x;
    for (; i < E; i += stride) atomicAdd(&cnt[dst[i]], 1);
}

// dsq[n] = rsqrt(in_deg + 1)   (self-loop contributes 1)
__global__ void k_dsq(const int* __restrict__ cnt, float* __restrict__ dsq, int n) {
    int i = blockIdx.x * blockDim.x + threadIdx.x;
    int stride = gridDim.x * blockDim.x;
    for (; i < n; i += stride) dsq[i] = rsqrtf((float)cnt[i] + 1.0f);
}

// exclusive scan, 3 phases
__global__ void k_scan1(const int* __restrict__ cnt, int* __restrict__ rowptr,
                        int* __restrict__ bsum, int n) {
    __shared__ int tmp[SCAN_B];
    int i = blockIdx.x * SCAN_B + threadIdx.x;
    int v = (i < n) ? cnt[i] : 0;
    tmp[threadIdx.x] = v;
    __syncthreads();
    int acc = v;
    for (int off = 1; off < SCAN_B; off <<= 1) {
        int t = (threadIdx.x >= off) ? tmp[threadIdx.x - off] : 0;
        __syncthreads();
        acc += t;
        tmp[threadIdx.x] = acc;
        __syncthreads();
    }
    if (i < n) rowptr[i] = acc - v;             // block-local exclusive
    if (threadIdx.x == SCAN_B - 1) bsum[blockIdx.x] = acc;  // block total
}
__global__ void k_scan2(int* __restrict__ bsum, int nb, int* __restrict__ rowptr, int E) {
    if (blockIdx.x == 0 && threadIdx.x == 0) {
        int run = 0;
        for (int b = 0; b < nb; ++b) { int t = bsum[b]; bsum[b] = run; run += t; }
        rowptr[N_NODES] = E;
    }
}
__global__ void k_scan3(int* __restrict__ rowptr, const int* __restrict__ bsum, int n) {
    int i = blockIdx.x * blockDim.x + threadIdx.x;
    int stride = gridDim.x * blockDim.x;
    for (; i < n; i += stride) rowptr[i] += bsum[i / SCAN_B];
}

// scatter edges into CSR slots, precomputing edge weight
__global__ void k_scatter(const int* __restrict__ src, const int* __restrict__ dst, int E,
                          const float* __restrict__ dsq, const int* __restrict__ rowptr,
                          int* __restrict__ cursor, int2* __restrict__ csr) {
    int i = blockIdx.x * blockDim.x + threadIdx.x;
    int stride = gridDim.x * blockDim.x;
    for (; i < E; i += stride) {
        int s = src[i], d = dst[i];
        int pos = rowptr[d] + atomicAdd(&cursor[d], 1);
        csr[pos] = make_int2(s, __float_as_int(dsq[s] * dsq[d]));
    }
}

// fused: pull-aggregate (64-dim) + dense 64x64 matmul + bias + activation
// one wave per node; lane = channel. ACT: 0 = leaky_relu(0.01), 1 = relu
template <int ACT>
__global__ __launch_bounds__(256) void k_layer64(
    const int* __restrict__ rowptr, const int2* __restrict__ csr,
    const float* __restrict__ dsq, const float* __restrict__ hin,
    const float* __restrict__ W, const float* __restrict__ b,
    float* __restrict__ hout) {
    __shared__ float Wl[64 * 64];
    __shared__ float rows[4][64];
    for (int i = threadIdx.x; i < 64 * 64; i += 256) Wl[i] = W[i];
    __syncthreads();

    int wid = threadIdx.x >> 6;
    int lane = threadIdx.x & 63;
    int node = blockIdx.x * 4 + wid;       // grid covers exactly N_NODES

    int start = rowptr[node], end = rowptr[node + 1];
    float dn = dsq[node];
    float acc = dn * dn * hin[node * 64 + lane];   // self-loop
    for (int k0 = start; k0 < end; k0 += 64) {
        int idx = k0 + lane;
        int2 p = (idx < end) ? csr[idx] : make_int2(0, 0);
        int nk = end - k0; if (nk > 64) nk = 64;
        for (int j = 0; j < nk; ++j) {
            int s = __shfl(p.x, j, 64);
            float w = __shfl(__int_as_float(p.y), j, 64);
            acc += w * hin[s * 64 + lane];
        }
    }
    rows[wid][lane] = acc;
    __syncthreads();
    float s = b[lane];
#pragma unroll
    for (int k = 0; k < 64; ++k) s += rows[wid][k] * Wl[k * 64 + lane];
    hout[node * 64 + lane] = ACT ? fmaxf(s, 0.0f) : (s > 0.0f ? s : 0.01f * s);
}

// layer 0: pull-aggregate x (12-dim, 4 edges/iter) + 12x64 matmul, leaky_relu
__global__ __launch_bounds__(256) void k_layer12(
    const int* __restrict__ rowptr, const int2* __restrict__ csr,
    const float* __restrict__ dsq, const float* __restrict__ x,
    const float* __restrict__ W, const float* __restrict__ b,
    float* __restrict__ hout) {
    __shared__ float Wl[12 * 64];
    __shared__ float rows[4][16];
    for (int i = threadIdx.x; i < 12 * 64; i += 256) Wl[i] = W[i];
    __syncthreads();

    int wid = threadIdx.x >> 6;
    int lane = threadIdx.x & 63;
    int node = blockIdx.x * 4 + wid;
    int j = lane >> 4, c = lane & 15;

    int start = rowptr[node], end = rowptr[node + 1];
    float dn = dsq[node];
    float acc = (j == 0 && c < 12) ? dn * dn * x[node * 12 + c] : 0.0f;
    for (int k0 = start; k0 < end; k0 += 4) {
        int idx = k0 + j;
        if (idx < end && c < 12) {
            int2 p = csr[idx];
            acc += __int_as_float(p.y) * x[p.x * 12 + c];
        }
    }
    acc += __shfl_xor(acc, 16, 64);
    acc += __shfl_xor(acc, 32, 64);
    if (lane < 16) rows[wid][lane] = acc;
    __syncthreads();
    float s = b[lane];
#pragma unroll
    for (int k = 0; k < 12; ++k) s += rows[wid][k] * Wl[k * 64 + lane];
    hout[node * 64 + lane] = (s > 0.0f) ? s : 0.01f * s;
}

// segmented mean-pool using sorted batch_index
__global__ void k_pool(const float* __restrict__ h, const int* __restrict__ batch,
                       float* __restrict__ psum, float* __restrict__ pcnt) {
    const int CHUNK = 256;
    int lane = threadIdx.x;
    int start = blockIdx.x * CHUNK;
    if (start >= N_NODES) return;
    int end = start + CHUNK;
    if (end > N_NODES) end = N_NODES;

    int curg = batch[start];
    float acc = 0.0f;
    int cnt = 0;
    for (int n = start; n < end; ++n) {
        int g = batch[n];
        if (g != curg) {
            atomicAdd(&psum[curg * EMB + lane], acc);
            if (lane == 0) atomicAdd(&pcnt[curg], (float)cnt);
            acc = 0.0f; cnt = 0; curg = g;
        }
        acc += h[n * EMB + lane];
        ++cnt;
    }
    atomicAdd(&psum[curg * EMB + lane], acc);
    if (lane == 0) atomicAdd(&pcnt[curg], (float)cnt);
}

__global__ void k_fc(const float* __restrict__ psum, const float* __restrict__ pcnt,
                     const float* __restrict__ Wfc, const float* __restrict__ bfc,
                     float* __restrict__ out) {
    int g = blockIdx.x;
    int lane = threadIdx.x;
    float v = psum[g * EMB + lane] * Wfc[lane];
#pragma unroll
    for (int off = 32; off; off >>= 1) v += __shfl_down(v, off, 64);
    if (lane == 0) {
        float c = fmaxf(pcnt[g], 1.0f);
        float z = v / c + bfc[0];
        out[g] = 1.0f / (1.0f + expf(-z));
    }
}

extern "C" void kernel_launch(void* const* d_in, const int* in_sizes, int n_in,
                              void* d_out, int out_size, void* d_ws, size_t ws_size,
                              hipStream_t stream) {
    const float* x     = (const float*)d_in[0];
    const int*   edge  = (const int*)d_in[1];
    const int*   batch = (const int*)d_in[2];
    const float* W0 = (const float*)d_in[3];
    const float* b0 = (const float*)d_in[4];
    const float* W1 = (const float*)d_in[5];
    const float* b1 = (const float*)d_in[6];
    const float* W2 = (const float*)d_in[7];
    const float* b2 = (const float*)d_in[8];
    const float* W3 = (const float*)d_in[9];
    const float* b3 = (const float*)d_in[10];
    const float* Wfc = (const float*)d_in[11];
    const float* bfc = (const float*)d_in[12];
    float* out = (float*)d_out;

    const int E = in_sizes[1] / 2;
    const int* src = edge;
    const int* dst = edge + E;

    // workspace layout (4-byte units)
    char* ws = (char*)d_ws;
    float* dsq    = (float*)ws;                   ws += sizeof(float) * N_NODES;
    int*   cnt    = (int*)ws;                     ws += sizeof(int) * N_NODES;
    int*   rowptr = (int*)ws;                     ws += sizeof(int) * (N_NODES + 1);
    int*   cursor = (int*)ws;                     ws += sizeof(int) * N_NODES;
    int*   bsum   = (int*)ws;                     ws += sizeof(int) * 128;
    ws = (char*)(((size_t)ws + 15) & ~(size_t)15);
    int2*  csr    = (int2*)ws;                    ws += sizeof(int2) * E;
    float* bufA   = (float*)ws;                   ws += sizeof(float) * N_NODES * EMB;
    float* bufB   = (float*)ws;                   ws += sizeof(float) * N_NODES * EMB;
    float* psum   = (float*)ws;                   ws += sizeof(float) * N_GRAPHS * EMB;
    float* pcnt   = (float*)ws;

    const int NB = (N_NODES + SCAN_B - 1) / SCAN_B;   // 98

    // ---- CSR build ----
    k_zero_i<<<256, 256, 0, stream>>>(cnt, N_NODES);
    k_hist<<<2048, 256, 0, stream>>>(dst, E, cnt);
    k_dsq<<<256, 256, 0, stream>>>(cnt, dsq, N_NODES);
    k_scan1<<<NB, SCAN_B, 0, stream>>>(cnt, rowptr, bsum, N_NODES);
    k_scan2<<<1, 64, 0, stream>>>(bsum, NB, rowptr, E);
    k_scan3<<<256, 256, 0, stream>>>(rowptr, bsum, N_NODES);
    k_zero_i<<<256, 256, 0, stream>>>(cursor, N_NODES);
    k_scatter<<<2048, 256, 0, stream>>>(src, dst, E, dsq, rowptr, cursor, csr);

    // ---- 4 fused GCN layers ----
    const int NBLK = N_NODES / 4;   // 25000, exact
    k_layer12<<<NBLK, 256, 0, stream>>>(rowptr, csr, dsq, x, W0, b0, bufA);
    k_layer64<0><<<NBLK, 256, 0, stream>>>(rowptr, csr, dsq, bufA, W1, b1, bufB);
    k_layer64<0><<<NBLK, 256, 0, stream>>>(rowptr, csr, dsq, bufB, W2, b2, bufA);
    k_layer64<1><<<NBLK, 256, 0, stream>>>(rowptr, csr, dsq, bufA, W3, b3, bufB);

    // ---- mean pool + fc + sigmoid ----
    k_zero_f<<<64, 256, 0, stream>>>(psum, N_GRAPHS * EMB + N_GRAPHS);
    k_pool<<<(N_NODES + 255) / 256, 64, 0, stream>>>(bufB, batch, psum, pcnt);
    k_fc<<<N_GRAPHS, 64, 0, stream>>>(psum, pcnt, Wfc, bfc, out);
}

// Round 3
// 1104.077 us; speedup vs baseline: 2.4272x; 1.0850x over previous
//
#include <hip/hip_runtime.h>
#include <math.h>

#define N_NODES 100000
#define N_GRAPHS 512
#define EMB 64
#define SCAN_B 1024

typedef unsigned int uint;

// ---------------- bf16 pack/unpack ----------------
__device__ __forceinline__ float bflo(uint u) { return __uint_as_float(u << 16); }
__device__ __forceinline__ float bfhi(uint u) { return __uint_as_float(u & 0xffff0000u); }
__device__ __forceinline__ uint rne16(float f) {
    uint u = __float_as_uint(f);
    return (u + 0x7fffu + ((u >> 16) & 1u)) >> 16;
}
__device__ __forceinline__ uint pack2(float a, float b) {
    return rne16(a) | (rne16(b) << 16);
}

// ---------------- utility ----------------
__global__ void k_zero_f(float* __restrict__ p, int n) {
    int i = blockIdx.x * blockDim.x + threadIdx.x;
    int stride = gridDim.x * blockDim.x;
    for (; i < n; i += stride) p[i] = 0.0f;
}
__global__ void k_zero_i(int* __restrict__ p, int n) {
    int i = blockIdx.x * blockDim.x + threadIdx.x;
    int stride = gridDim.x * blockDim.x;
    for (; i < n; i += stride) p[i] = 0;
}

__global__ void k_hist(const int* __restrict__ dst, int E, int* __restrict__ cnt) {
    int i = blockIdx.x * blockDim.x + threadIdx.x;
    int stride = gridDim.x * blockDim.x;
    for (; i < E; i += stride) atomicAdd(&cnt[dst[i]], 1);
}

__global__ void k_dsq(const int* __restrict__ cnt, float* __restrict__ dsq, int n) {
    int i = blockIdx.x * blockDim.x + threadIdx.x;
    int stride = gridDim.x * blockDim.x;
    for (; i < n; i += stride) dsq[i] = rsqrtf((float)cnt[i] + 1.0f);
}

// xp = dsq[n] * x   (pre-scaled layer-0 input)
__global__ void k_xprep(const float* __restrict__ x, const float* __restrict__ dsq,
                        float* __restrict__ xp) {
    int i = blockIdx.x * blockDim.x + threadIdx.x;
    int stride = gridDim.x * blockDim.x;
    const int total = N_NODES * 12;
    for (; i < total; i += stride) xp[i] = x[i] * dsq[i / 12];
}

// exclusive scan, 3 phases
__global__ void k_scan1(const int* __restrict__ cnt, int* __restrict__ rowptr,
                        int* __restrict__ bsum, int n) {
    __shared__ int tmp[SCAN_B];
    int i = blockIdx.x * SCAN_B + threadIdx.x;
    int v = (i < n) ? cnt[i] : 0;
    tmp[threadIdx.x] = v;
    __syncthreads();
    int acc = v;
    for (int off = 1; off < SCAN_B; off <<= 1) {
        int t = (threadIdx.x >= off) ? tmp[threadIdx.x - off] : 0;
        __syncthreads();
        acc += t;
        tmp[threadIdx.x] = acc;
        __syncthreads();
    }
    if (i < n) rowptr[i] = acc - v;
    if (threadIdx.x == SCAN_B - 1) bsum[blockIdx.x] = acc;
}
__global__ void k_scan2(int* __restrict__ bsum, int nb, int* __restrict__ rowptr, int E) {
    if (blockIdx.x == 0 && threadIdx.x == 0) {
        int run = 0;
        for (int b = 0; b < nb; ++b) { int t = bsum[b]; bsum[b] = run; run += t; }
        rowptr[N_NODES] = E;
    }
}
__global__ void k_scan3(int* __restrict__ rowptr, const int* __restrict__ bsum,
                        int* __restrict__ cursor, int n) {
    int i = blockIdx.x * blockDim.x + threadIdx.x;
    int stride = gridDim.x * blockDim.x;
    for (; i < n; i += stride) {
        int v = rowptr[i] + bsum[i / SCAN_B];
        rowptr[i] = v;
        cursor[i] = v;
    }
}

// scatter src indices into CSR slots (weight is separable, not stored)
__global__ void k_scatter(const int* __restrict__ src, const int* __restrict__ dst, int E,
                          int* __restrict__ cursor, int* __restrict__ csr) {
    int i = blockIdx.x * blockDim.x + threadIdx.x;
    int stride = gridDim.x * blockDim.x;
    for (; i < E; i += stride) {
        int s = src[i], d = dst[i];
        int pos = atomicAdd(&cursor[d], 1);
        csr[pos] = s;
    }
}

// fused 64-dim layer: pull-aggregate bf16 rows + 64x64 matmul + act
// hin2: packed bf16x2 of h' = dsq*h (32 uints/node).
// agg[d] = dsq[d] * (h'[d] + sum_src h'[src])
// LAST=0: store packed bf16 of dsq*act  (pre-scaled for next layer)
// LAST=1: store raw f32 act
template <int ACT, int LAST>
__global__ __launch_bounds__(256) void k_layer64(
    const int* __restrict__ rowptr, const int* __restrict__ csr,
    const float* __restrict__ dsq, const uint* __restrict__ hin2,
    const float* __restrict__ W, const float* __restrict__ b,
    uint* __restrict__ hout2, float* __restrict__ houtf) {
    __shared__ float Wl[64 * 64];
    __shared__ float rows[4][64];
    for (int i = threadIdx.x; i < 64 * 64; i += 256) Wl[i] = W[i];

    int wid = threadIdx.x >> 6;
    int lane = threadIdx.x & 63;
    int node = blockIdx.x * 4 + wid;
    int half = lane >> 5;
    int c = lane & 31;

    int start = rowptr[node], end = rowptr[node + 1];
    float dn = dsq[node];

    uint us = hin2[node * 32 + c];       // self-loop row (h' already dsq-scaled)
    float ax = half ? 0.0f : bflo(us);
    float ay = half ? 0.0f : bfhi(us);

    for (int k0 = start; k0 < end; k0 += 64) {
        int idx = k0 + lane;
        int s = (idx < end) ? csr[idx] : 0;
        int nk = end - k0; if (nk > 64) nk = 64;
        int np = (nk + 1) >> 1;
        for (int jj = 0; jj < np; ++jj) {
            int e = 2 * jj + half;       // half-wave h handles edge parity h
            int sj = __shfl(s, e, 64);
            if (e < nk) {
                uint u = hin2[sj * 32 + c];
                ax += bflo(u);
                ay += bfhi(u);
            }
        }
    }
    ax += __shfl_xor(ax, 32, 64);
    ay += __shfl_xor(ay, 32, 64);
    if (lane < 32) {
        rows[wid][2 * c]     = dn * ax;
        rows[wid][2 * c + 1] = dn * ay;
    }
    __syncthreads();

    float sacc = b[lane];
#pragma unroll 16
    for (int k = 0; k < 64; ++k) sacc += rows[wid][k] * Wl[k * 64 + lane];
    float val = ACT ? fmaxf(sacc, 0.0f) : (sacc > 0.0f ? sacc : 0.01f * sacc);

    if (LAST) {
        houtf[node * 64 + lane] = val;
    } else {
        float sv = dn * val;             // pre-scale for next layer's gather
        float pv = __shfl_xor(sv, 1, 64);
        if ((lane & 1) == 0) hout2[node * 32 + (lane >> 1)] = pack2(sv, pv);
    }
}

// layer 0: pull-aggregate xp (12-dim f32) + 12x64 matmul + leaky, bf16 packed out
__global__ __launch_bounds__(256) void k_layer12(
    const int* __restrict__ rowptr, const int* __restrict__ csr,
    const float* __restrict__ dsq, const float* __restrict__ xp,
    const float* __restrict__ W, const float* __restrict__ b,
    uint* __restrict__ hout2) {
    __shared__ float Wl[12 * 64];
    __shared__ float rows[4][16];
    for (int i = threadIdx.x; i < 12 * 64; i += 256) Wl[i] = W[i];

    int wid = threadIdx.x >> 6;
    int lane = threadIdx.x & 63;
    int node = blockIdx.x * 4 + wid;
    int j = lane >> 4, c = lane & 15;

    int start = rowptr[node], end = rowptr[node + 1];
    float dn = dsq[node];
    float acc = (j == 0 && c < 12) ? xp[node * 12 + c] : 0.0f;  // self-loop
    for (int k0 = start; k0 < end; k0 += 4) {
        int idx = k0 + j;
        if (idx < end && c < 12) {
            int s = csr[idx];
            acc += xp[s * 12 + c];
        }
    }
    acc += __shfl_xor(acc, 16, 64);
    acc += __shfl_xor(acc, 32, 64);
    if (lane < 16) rows[wid][lane] = dn * acc;
    __syncthreads();

    float sacc = b[lane];
#pragma unroll
    for (int k = 0; k < 12; ++k) sacc += rows[wid][k] * Wl[k * 64 + lane];
    float val = (sacc > 0.0f) ? sacc : 0.01f * sacc;
    float sv = dn * val;
    float pv = __shfl_xor(sv, 1, 64);
    if ((lane & 1) == 0) hout2[node * 32 + (lane >> 1)] = pack2(sv, pv);
}

// segmented mean-pool using sorted batch_index
__global__ void k_pool(const float* __restrict__ h, const int* __restrict__ batch,
                       float* __restrict__ psum, float* __restrict__ pcnt) {
    const int CHUNK = 256;
    int lane = threadIdx.x;
    int start = blockIdx.x * CHUNK;
    if (start >= N_NODES) return;
    int end = start + CHUNK;
    if (end > N_NODES) end = N_NODES;

    int curg = batch[start];
    float acc = 0.0f;
    int cnt = 0;
    for (int n = start; n < end; ++n) {
        int g = batch[n];
        if (g != curg) {
            atomicAdd(&psum[curg * EMB + lane], acc);
            if (lane == 0) atomicAdd(&pcnt[curg], (float)cnt);
            acc = 0.0f; cnt = 0; curg = g;
        }
        acc += h[n * EMB + lane];
        ++cnt;
    }
    atomicAdd(&psum[curg * EMB + lane], acc);
    if (lane == 0) atomicAdd(&pcnt[curg], (float)cnt);
}

__global__ void k_fc(const float* __restrict__ psum, const float* __restrict__ pcnt,
                     const float* __restrict__ Wfc, const float* __restrict__ bfc,
                     float* __restrict__ out) {
    int g = blockIdx.x;
    int lane = threadIdx.x;
    float v = psum[g * EMB + lane] * Wfc[lane];
#pragma unroll
    for (int off = 32; off; off >>= 1) v += __shfl_down(v, off, 64);
    if (lane == 0) {
        float c = fmaxf(pcnt[g], 1.0f);
        float z = v / c + bfc[0];
        out[g] = 1.0f / (1.0f + expf(-z));
    }
}

extern "C" void kernel_launch(void* const* d_in, const int* in_sizes, int n_in,
                              void* d_out, int out_size, void* d_ws, size_t ws_size,
                              hipStream_t stream) {
    const float* x     = (const float*)d_in[0];
    const int*   edge  = (const int*)d_in[1];
    const int*   batch = (const int*)d_in[2];
    const float* W0 = (const float*)d_in[3];
    const float* b0 = (const float*)d_in[4];
    const float* W1 = (const float*)d_in[5];
    const float* b1 = (const float*)d_in[6];
    const float* W2 = (const float*)d_in[7];
    const float* b2 = (const float*)d_in[8];
    const float* W3 = (const float*)d_in[9];
    const float* b3 = (const float*)d_in[10];
    const float* Wfc = (const float*)d_in[11];
    const float* bfc = (const float*)d_in[12];
    float* out = (float*)d_out;

    const int E = in_sizes[1] / 2;
    const int* src = edge;
    const int* dst = edge + E;

    // workspace layout
    char* ws = (char*)d_ws;
    float* dsq    = (float*)ws;                   ws += sizeof(float) * N_NODES;
    int*   cnt    = (int*)ws;                     ws += sizeof(int) * N_NODES;
    int*   rowptr = (int*)ws;                     ws += sizeof(int) * (N_NODES + 1);
    int*   cursor = (int*)ws;                     ws += sizeof(int) * N_NODES;
    int*   bsum   = (int*)ws;                     ws += sizeof(int) * 128;
    ws = (char*)(((size_t)ws + 15) & ~(size_t)15);
    float* xp     = (float*)ws;                   ws += sizeof(float) * N_NODES * 12;
    int*   csr    = (int*)ws;                     ws += sizeof(int) * E;
    uint*  bufA   = (uint*)ws;                    ws += sizeof(uint) * N_NODES * 32;
    uint*  bufB   = (uint*)ws;                    ws += sizeof(uint) * N_NODES * 32;
    float* bufF   = (float*)ws;                   ws += sizeof(float) * N_NODES * EMB;
    float* psum   = (float*)ws;                   ws += sizeof(float) * N_GRAPHS * EMB;
    float* pcnt   = (float*)ws;

    const int NB = (N_NODES + SCAN_B - 1) / SCAN_B;   // 98

    // ---- CSR build ----
    k_zero_i<<<256, 256, 0, stream>>>(cnt, N_NODES);
    k_hist<<<2048, 256, 0, stream>>>(dst, E, cnt);
    k_dsq<<<256, 256, 0, stream>>>(cnt, dsq, N_NODES);
    k_xprep<<<1024, 256, 0, stream>>>(x, dsq, xp);
    k_scan1<<<NB, SCAN_B, 0, stream>>>(cnt, rowptr, bsum, N_NODES);
    k_scan2<<<1, 64, 0, stream>>>(bsum, NB, rowptr, E);
    k_scan3<<<256, 256, 0, stream>>>(rowptr, bsum, cursor, N_NODES);
    k_scatter<<<2048, 256, 0, stream>>>(src, dst, E, cursor, csr);

    // ---- 4 fused GCN layers ----
    const int NBLK = N_NODES / 4;   // 25000, exact
    k_layer12<<<NBLK, 256, 0, stream>>>(rowptr, csr, dsq, xp, W0, b0, bufA);
    k_layer64<0, 0><<<NBLK, 256, 0, stream>>>(rowptr, csr, dsq, bufA, W1, b1, bufB, nullptr);
    k_layer64<0, 0><<<NBLK, 256, 0, stream>>>(rowptr, csr, dsq, bufB, W2, b2, bufA, nullptr);
    k_layer64<1, 1><<<NBLK, 256, 0, stream>>>(rowptr, csr, dsq, bufA, W3, b3, nullptr, bufF);

    // ---- mean pool + fc + sigmoid ----
    k_zero_f<<<64, 256, 0, stream>>>(psum, N_GRAPHS * EMB + N_GRAPHS);
    k_pool<<<(N_NODES + 255) / 256, 64, 0, stream>>>(bufF, batch, psum, pcnt);
    k_fc<<<N_GRAPHS, 64, 0, stream>>>(psum, pcnt, Wfc, bfc, out);
}

// Round 4
// 981.317 us; speedup vs baseline: 2.7308x; 1.1251x over previous
//
#include <hip/hip_runtime.h>
#include <math.h>

#define N_NODES 100000
#define N_GRAPHS 512
#define EMB 64
#define SCAN_B 1024
#define NBKT 98          // ceil(100000 / 1024) buckets of 1024 nodes
#define CHUNK_E 4096     // edges per k_bscatter block

typedef unsigned int uint;

// ---------------- bf16 pack/unpack ----------------
__device__ __forceinline__ float bflo(uint u) { return __uint_as_float(u << 16); }
__device__ __forceinline__ float bfhi(uint u) { return __uint_as_float(u & 0xffff0000u); }
__device__ __forceinline__ uint rne16(float f) {
    uint u = __float_as_uint(f);
    return (u + 0x7fffu + ((u >> 16) & 1u)) >> 16;
}
__device__ __forceinline__ uint pack2(float a, float b) {
    return rne16(a) | (rne16(b) << 16);
}

// ---------------- utility ----------------
__global__ void k_zero_f(float* __restrict__ p, int n) {
    int i = blockIdx.x * blockDim.x + threadIdx.x;
    int stride = gridDim.x * blockDim.x;
    for (; i < n; i += stride) p[i] = 0.0f;
}
__global__ void k_zero_i(int* __restrict__ p, int n) {
    int i = blockIdx.x * blockDim.x + threadIdx.x;
    int stride = gridDim.x * blockDim.x;
    for (; i < n; i += stride) p[i] = 0;
}

__global__ void k_hist(const int* __restrict__ dst, int E, int* __restrict__ cnt) {
    int i = blockIdx.x * blockDim.x + threadIdx.x;
    int stride = gridDim.x * blockDim.x;
    for (; i < E; i += stride) atomicAdd(&cnt[dst[i]], 1);
}

__global__ void k_dsq(const int* __restrict__ cnt, float* __restrict__ dsq, int n) {
    int i = blockIdx.x * blockDim.x + threadIdx.x;
    int stride = gridDim.x * blockDim.x;
    for (; i < n; i += stride) dsq[i] = rsqrtf((float)cnt[i] + 1.0f);
}

// xp = dsq[n] * x   (pre-scaled layer-0 input)
__global__ void k_xprep(const float* __restrict__ x, const float* __restrict__ dsq,
                        float* __restrict__ xp) {
    int i = blockIdx.x * blockDim.x + threadIdx.x;
    int stride = gridDim.x * blockDim.x;
    const int total = N_NODES * 12;
    for (; i < total; i += stride) xp[i] = x[i] * dsq[i / 12];
}

// exclusive scan of node counts, 3 phases
__global__ void k_scan1(const int* __restrict__ cnt, int* __restrict__ rowptr,
                        int* __restrict__ bsum, int n) {
    __shared__ int tmp[SCAN_B];
    int i = blockIdx.x * SCAN_B + threadIdx.x;
    int v = (i < n) ? cnt[i] : 0;
    tmp[threadIdx.x] = v;
    __syncthreads();
    int acc = v;
    for (int off = 1; off < SCAN_B; off <<= 1) {
        int t = (threadIdx.x >= off) ? tmp[threadIdx.x - off] : 0;
        __syncthreads();
        acc += t;
        tmp[threadIdx.x] = acc;
        __syncthreads();
    }
    if (i < n) rowptr[i] = acc - v;
    if (threadIdx.x == SCAN_B - 1) bsum[blockIdx.x] = acc;
}
__global__ void k_scan2(int* __restrict__ bsum, int nb, int* __restrict__ rowptr, int E) {
    if (blockIdx.x == 0 && threadIdx.x == 0) {
        int run = 0;
        for (int b = 0; b < nb; ++b) { int t = bsum[b]; bsum[b] = run; run += t; }
        rowptr[N_NODES] = E;
    }
}
__global__ void k_scan3(int* __restrict__ rowptr, const int* __restrict__ bsum,
                        int* __restrict__ cursor, int n) {
    int i = blockIdx.x * blockDim.x + threadIdx.x;
    int stride = gridDim.x * blockDim.x;
    for (; i < n; i += stride) {
        int v = rowptr[i] + bsum[i / SCAN_B];
        rowptr[i] = v;
        cursor[i] = v;
    }
}

// bucket counts from node counts (bucket b = nodes [b*1024, b*1024+1024))
__global__ __launch_bounds__(256) void k_bcnt(const int* __restrict__ cnt,
                                              int* __restrict__ bcnt) {
    __shared__ int r[256];
    int b = blockIdx.x;
    int base = b << 10;
    int t = threadIdx.x;
    int s = 0;
    for (int i = t; i < 1024; i += 256) {
        int n = base + i;
        if (n < N_NODES) s += cnt[n];
    }
    r[t] = s;
    __syncthreads();
    for (int off = 128; off; off >>= 1) {
        if (t < off) r[t] += r[t + off];
        __syncthreads();
    }
    if (t == 0) bcnt[b] = r[0];
}

__global__ void k_bscan(const int* __restrict__ bcnt, int* __restrict__ bcursor) {
    if (blockIdx.x == 0 && threadIdx.x == 0) {
        int run = 0;
        for (int b = 0; b < NBKT; ++b) { bcursor[b] = run; run += bcnt[b]; }
    }
}

// counting-sort pass: partition edges into dst-buckets with LDS staging so
// global writes are coalesced per-bucket runs. sp[pos] = (src, dst).
__global__ __launch_bounds__(256) void k_bscatter(
    const int* __restrict__ src, const int* __restrict__ dst, int E,
    int* __restrict__ bcursor, int2* __restrict__ sp) {
    __shared__ int wcnt[NBKT];
    __shared__ int wbase[NBKT];
    __shared__ int lofs[NBKT];
    __shared__ int lcur[NBKT];
    __shared__ int2 stage[CHUNK_E];
    __shared__ short sbkt[CHUNK_E];

    int e0 = blockIdx.x * CHUNK_E;
    int e1 = e0 + CHUNK_E;
    if (e1 > E) e1 = E;
    int t = threadIdx.x;

    for (int i = t; i < NBKT; i += 256) { wcnt[i] = 0; lcur[i] = 0; }
    __syncthreads();
    for (int i = e0 + t; i < e1; i += 256) atomicAdd(&wcnt[dst[i] >> 10], 1);
    __syncthreads();
    if (t < NBKT) wbase[t] = atomicAdd(&bcursor[t], wcnt[t]);
    if (t == 0) {
        int run = 0;
        for (int b = 0; b < NBKT; ++b) { lofs[b] = run; run += wcnt[b]; }
    }
    __syncthreads();
    for (int i = e0 + t; i < e1; i += 256) {
        int d = dst[i];
        int b = d >> 10;
        int l = lofs[b] + atomicAdd(&lcur[b], 1);
        stage[l] = make_int2(src[i], d);
        sbkt[l] = (short)b;
    }
    __syncthreads();
    int n = e1 - e0;
    for (int k = t; k < n; k += 256) {
        int b = sbkt[k];
        sp[wbase[b] + (k - lofs[b])] = stage[k];
    }
}

// CSR scatter over bucket-ordered pairs: writes localized to ~131KB windows
__global__ void k_scatter2(const int2* __restrict__ sp, int E,
                           int* __restrict__ cursor, int* __restrict__ csr) {
    int i = blockIdx.x * blockDim.x + threadIdx.x;
    int stride = gridDim.x * blockDim.x;
    for (; i < E; i += stride) {
        int2 p = sp[i];
        int pos = atomicAdd(&cursor[p.y], 1);
        csr[pos] = p.x;
    }
}

// fused 64-dim layer: pull-aggregate bf16 rows + 64x64 matmul + act
template <int ACT, int LAST>
__global__ __launch_bounds__(256) void k_layer64(
    const int* __restrict__ rowptr, const int* __restrict__ csr,
    const float* __restrict__ dsq, const uint* __restrict__ hin2,
    const float* __restrict__ W, const float* __restrict__ b,
    uint* __restrict__ hout2, float* __restrict__ houtf) {
    __shared__ float Wl[64 * 64];
    __shared__ float rows[4][64];
    for (int i = threadIdx.x; i < 64 * 64; i += 256) Wl[i] = W[i];

    int wid = threadIdx.x >> 6;
    int lane = threadIdx.x & 63;
    int node = blockIdx.x * 4 + wid;
    int half = lane >> 5;
    int c = lane & 31;

    int start = rowptr[node], end = rowptr[node + 1];
    float dn = dsq[node];

    uint us = hin2[node * 32 + c];
    float ax = half ? 0.0f : bflo(us);
    float ay = half ? 0.0f : bfhi(us);

    for (int k0 = start; k0 < end; k0 += 64) {
        int idx = k0 + lane;
        int s = (idx < end) ? csr[idx] : 0;
        int nk = end - k0; if (nk > 64) nk = 64;
        int np = (nk + 1) >> 1;
        for (int jj = 0; jj < np; ++jj) {
            int e = 2 * jj + half;
            int sj = __shfl(s, e, 64);
            if (e < nk) {
                uint u = hin2[sj * 32 + c];
                ax += bflo(u);
                ay += bfhi(u);
            }
        }
    }
    ax += __shfl_xor(ax, 32, 64);
    ay += __shfl_xor(ay, 32, 64);
    if (lane < 32) {
        rows[wid][2 * c]     = dn * ax;
        rows[wid][2 * c + 1] = dn * ay;
    }
    __syncthreads();

    float sacc = b[lane];
#pragma unroll 16
    for (int k = 0; k < 64; ++k) sacc += rows[wid][k] * Wl[k * 64 + lane];
    float val = ACT ? fmaxf(sacc, 0.0f) : (sacc > 0.0f ? sacc : 0.01f * sacc);

    if (LAST) {
        houtf[node * 64 + lane] = val;
    } else {
        float sv = dn * val;
        float pv = __shfl_xor(sv, 1, 64);
        if ((lane & 1) == 0) hout2[node * 32 + (lane >> 1)] = pack2(sv, pv);
    }
}

// layer 0: pull-aggregate xp (12-dim f32) + 12x64 matmul + leaky, bf16 packed out
__global__ __launch_bounds__(256) void k_layer12(
    const int* __restrict__ rowptr, const int* __restrict__ csr,
    const float* __restrict__ dsq, const float* __restrict__ xp,
    const float* __restrict__ W, const float* __restrict__ b,
    uint* __restrict__ hout2) {
    __shared__ float Wl[12 * 64];
    __shared__ float rows[4][16];
    for (int i = threadIdx.x; i < 12 * 64; i += 256) Wl[i] = W[i];

    int wid = threadIdx.x >> 6;
    int lane = threadIdx.x & 63;
    int node = blockIdx.x * 4 + wid;
    int j = lane >> 4, c = lane & 15;

    int start = rowptr[node], end = rowptr[node + 1];
    float dn = dsq[node];
    float acc = (j == 0 && c < 12) ? xp[node * 12 + c] : 0.0f;
    for (int k0 = start; k0 < end; k0 += 4) {
        int idx = k0 + j;
        if (idx < end && c < 12) {
            int s = csr[idx];
            acc += xp[s * 12 + c];
        }
    }
    acc += __shfl_xor(acc, 16, 64);
    acc += __shfl_xor(acc, 32, 64);
    if (lane < 16) rows[wid][lane] = dn * acc;
    __syncthreads();

    float sacc = b[lane];
#pragma unroll
    for (int k = 0; k < 12; ++k) sacc += rows[wid][k] * Wl[k * 64 + lane];
    float val = (sacc > 0.0f) ? sacc : 0.01f * sacc;
    float sv = dn * val;
    float pv = __shfl_xor(sv, 1, 64);
    if ((lane & 1) == 0) hout2[node * 32 + (lane >> 1)] = pack2(sv, pv);
}

// segmented mean-pool using sorted batch_index
__global__ void k_pool(const float* __restrict__ h, const int* __restrict__ batch,
                       float* __restrict__ psum, float* __restrict__ pcnt) {
    const int CHUNK = 256;
    int lane = threadIdx.x;
    int start = blockIdx.x * CHUNK;
    if (start >= N_NODES) return;
    int end = start + CHUNK;
    if (end > N_NODES) end = N_NODES;

    int curg = batch[start];
    float acc = 0.0f;
    int cnt = 0;
    for (int n = start; n < end; ++n) {
        int g = batch[n];
        if (g != curg) {
            atomicAdd(&psum[curg * EMB + lane], acc);
            if (lane == 0) atomicAdd(&pcnt[curg], (float)cnt);
            acc = 0.0f; cnt = 0; curg = g;
        }
        acc += h[n * EMB + lane];
        ++cnt;
    }
    atomicAdd(&psum[curg * EMB + lane], acc);
    if (lane == 0) atomicAdd(&pcnt[curg], (float)cnt);
}

__global__ void k_fc(const float* __restrict__ psum, const float* __restrict__ pcnt,
                     const float* __restrict__ Wfc, const float* __restrict__ bfc,
                     float* __restrict__ out) {
    int g = blockIdx.x;
    int lane = threadIdx.x;
    float v = psum[g * EMB + lane] * Wfc[lane];
#pragma unroll
    for (int off = 32; off; off >>= 1) v += __shfl_down(v, off, 64);
    if (lane == 0) {
        float c = fmaxf(pcnt[g], 1.0f);
        float z = v / c + bfc[0];
        out[g] = 1.0f / (1.0f + expf(-z));
    }
}

extern "C" void kernel_launch(void* const* d_in, const int* in_sizes, int n_in,
                              void* d_out, int out_size, void* d_ws, size_t ws_size,
                              hipStream_t stream) {
    const float* x     = (const float*)d_in[0];
    const int*   edge  = (const int*)d_in[1];
    const int*   batch = (const int*)d_in[2];
    const float* W0 = (const float*)d_in[3];
    const float* b0 = (const float*)d_in[4];
    const float* W1 = (const float*)d_in[5];
    const float* b1 = (const float*)d_in[6];
    const float* W2 = (const float*)d_in[7];
    const float* b2 = (const float*)d_in[8];
    const float* W3 = (const float*)d_in[9];
    const float* b3 = (const float*)d_in[10];
    const float* Wfc = (const float*)d_in[11];
    const float* bfc = (const float*)d_in[12];
    float* out = (float*)d_out;

    const int E = in_sizes[1] / 2;
    const int* src = edge;
    const int* dst = edge + E;

    // workspace layout
    char* ws = (char*)d_ws;
    float* dsq    = (float*)ws;                   ws += sizeof(float) * N_NODES;
    int*   cnt    = (int*)ws;                     ws += sizeof(int) * N_NODES;
    int*   rowptr = (int*)ws;                     ws += sizeof(int) * (N_NODES + 1);
    int*   cursor = (int*)ws;                     ws += sizeof(int) * N_NODES;
    int*   bsum   = (int*)ws;                     ws += sizeof(int) * 128;
    int*   bcnt   = (int*)ws;                     ws += sizeof(int) * 128;
    int*   bcursor= (int*)ws;                     ws += sizeof(int) * 128;
    ws = (char*)(((size_t)ws + 15) & ~(size_t)15);
    float* xp     = (float*)ws;                   ws += sizeof(float) * N_NODES * 12;
    int*   csr    = (int*)ws;                     ws += sizeof(int) * E;
    uint*  bufA   = (uint*)ws;                    ws += sizeof(uint) * N_NODES * 32;
    uint*  bufB   = (uint*)ws;                    ws += sizeof(uint) * N_NODES * 32;
    float* bufF   = (float*)ws;                   ws += sizeof(float) * N_NODES * EMB;
    float* psum   = (float*)ws;                   ws += sizeof(float) * N_GRAPHS * EMB;
    float* pcnt   = (float*)ws;
    int2*  sp     = (int2*)bufA;   // sorted pairs alias bufA+bufB (dead until layer 0)

    const int NB = (N_NODES + SCAN_B - 1) / SCAN_B;   // 98

    // ---- degree / norms / rowptr ----
    k_zero_i<<<256, 256, 0, stream>>>(cnt, N_NODES);
    k_hist<<<2048, 256, 0, stream>>>(dst, E, cnt);
    k_dsq<<<256, 256, 0, stream>>>(cnt, dsq, N_NODES);
    k_xprep<<<1024, 256, 0, stream>>>(x, dsq, xp);
    k_scan1<<<NB, SCAN_B, 0, stream>>>(cnt, rowptr, bsum, N_NODES);
    k_scan2<<<1, 64, 0, stream>>>(bsum, NB, rowptr, E);
    k_scan3<<<256, 256, 0, stream>>>(rowptr, bsum, cursor, N_NODES);

    // ---- bucket counting-sort + localized CSR scatter ----
    k_bcnt<<<NBKT, 256, 0, stream>>>(cnt, bcnt);
    k_bscan<<<1, 64, 0, stream>>>(bcnt, bcursor);
    k_bscatter<<<(E + CHUNK_E - 1) / CHUNK_E, 256, 0, stream>>>(src, dst, E, bcursor, sp);
    k_scatter2<<<2048, 256, 0, stream>>>(sp, E, cursor, csr);

    // ---- 4 fused GCN layers ----
    const int NBLK = N_NODES / 4;   // 25000, exact
    k_layer12<<<NBLK, 256, 0, stream>>>(rowptr, csr, dsq, xp, W0, b0, bufA);
    k_layer64<0, 0><<<NBLK, 256, 0, stream>>>(rowptr, csr, dsq, bufA, W1, b1, bufB, nullptr);
    k_layer64<0, 0><<<NBLK, 256, 0, stream>>>(rowptr, csr, dsq, bufB, W2, b2, bufA, nullptr);
    k_layer64<1, 1><<<NBLK, 256, 0, stream>>>(rowptr, csr, dsq, bufA, W3, b3, nullptr, bufF);

    // ---- mean pool + fc + sigmoid ----
    k_zero_f<<<64, 256, 0, stream>>>(psum, N_GRAPHS * EMB + N_GRAPHS);
    k_pool<<<(N_NODES + 255) / 256, 64, 0, stream>>>(bufF, batch, psum, pcnt);
    k_fc<<<N_GRAPHS, 64, 0, stream>>>(psum, pcnt, Wfc, bfc, out);
}

// Round 5
// 675.365 us; speedup vs baseline: 3.9680x; 1.4530x over previous
//
#include <hip/hip_runtime.h>
#include <math.h>

#define N_NODES 100000
#define N_GRAPHS 512
#define EMB 64
#define SCAN_B 1024
#define NBKT 98          // ceil(100000 / 1024) buckets of 1024 nodes
#define CHUNK_E 4096     // edges per k_bscatter block

typedef unsigned int uint;

// ---------------- bf16 pack/unpack ----------------
__device__ __forceinline__ float bflo(uint u) { return __uint_as_float(u << 16); }
__device__ __forceinline__ float bfhi(uint u) { return __uint_as_float(u & 0xffff0000u); }
__device__ __forceinline__ uint rne16(float f) {
    uint u = __float_as_uint(f);
    return (u + 0x7fffu + ((u >> 16) & 1u)) >> 16;
}
__device__ __forceinline__ uint pack2(float a, float b) {
    return rne16(a) | (rne16(b) << 16);
}

// ---------------- utility ----------------
__global__ void k_zero_f(float* __restrict__ p, int n) {
    int i = blockIdx.x * blockDim.x + threadIdx.x;
    int stride = gridDim.x * blockDim.x;
    for (; i < n; i += stride) p[i] = 0.0f;
}
__global__ void k_zero_i(int* __restrict__ p, int n) {
    int i = blockIdx.x * blockDim.x + threadIdx.x;
    int stride = gridDim.x * blockDim.x;
    for (; i < n; i += stride) p[i] = 0;
}

// bucket histogram of dst>>10, LDS-staged
__global__ __launch_bounds__(256) void k_bhist(const int* __restrict__ dst, int E,
                                               int* __restrict__ bcnt) {
    __shared__ int w[NBKT];
    for (int i = threadIdx.x; i < NBKT; i += 256) w[i] = 0;
    __syncthreads();
    int i = blockIdx.x * 256 + threadIdx.x;
    int stride = gridDim.x * 256;
    for (; i < E; i += stride) atomicAdd(&w[dst[i] >> 10], 1);
    __syncthreads();
    for (int t = threadIdx.x; t < NBKT; t += 256)
        if (w[t]) atomicAdd(&bcnt[t], w[t]);
}

__global__ void k_bscan(const int* __restrict__ bcnt, int* __restrict__ bstart,
                        int* __restrict__ bcursor) {
    if (blockIdx.x == 0 && threadIdx.x == 0) {
        int run = 0;
        for (int b = 0; b < NBKT; ++b) { bstart[b] = run; bcursor[b] = run; run += bcnt[b]; }
        bstart[NBKT] = run;
    }
}

// counting-sort pass: partition edges into dst-buckets with LDS staging so
// global writes are coalesced per-bucket runs. sp[pos] = (src, dst).
__global__ __launch_bounds__(256) void k_bscatter(
    const int* __restrict__ src, const int* __restrict__ dst, int E,
    int* __restrict__ bcursor, int2* __restrict__ sp) {
    __shared__ int wcnt[NBKT];
    __shared__ int wbase[NBKT];
    __shared__ int lofs[NBKT];
    __shared__ int lcur[NBKT];
    __shared__ int2 stage[CHUNK_E];
    __shared__ short sbkt[CHUNK_E];

    int e0 = blockIdx.x * CHUNK_E;
    int e1 = e0 + CHUNK_E;
    if (e1 > E) e1 = E;
    int t = threadIdx.x;

    for (int i = t; i < NBKT; i += 256) { wcnt[i] = 0; lcur[i] = 0; }
    __syncthreads();
    for (int i = e0 + t; i < e1; i += 256) atomicAdd(&wcnt[dst[i] >> 10], 1);
    __syncthreads();
    if (t < NBKT) wbase[t] = atomicAdd(&bcursor[t], wcnt[t]);
    if (t == 0) {
        int run = 0;
        for (int b = 0; b < NBKT; ++b) { lofs[b] = run; run += wcnt[b]; }
    }
    __syncthreads();
    for (int i = e0 + t; i < e1; i += 256) {
        int d = dst[i];
        int b = d >> 10;
        int l = lofs[b] + atomicAdd(&lcur[b], 1);
        stage[l] = make_int2(src[i], d);
        sbkt[l] = (short)b;
    }
    __syncthreads();
    int n = e1 - e0;
    for (int k = t; k < n; k += 256) {
        int b = sbkt[k];
        sp[wbase[b] + (k - lofs[b])] = stage[k];
    }
}

// per-node counts + dsq from bucket-sorted pairs (one block per bucket)
__global__ __launch_bounds__(256) void k_cnt2(const int2* __restrict__ sp,
                                              const int* __restrict__ bstart,
                                              int* __restrict__ cnt,
                                              float* __restrict__ dsq) {
    __shared__ int lcnt[1024];
    int b = blockIdx.x;
    int base = b << 10;
    for (int j = threadIdx.x; j < 1024; j += 256) lcnt[j] = 0;
    __syncthreads();
    int s0 = bstart[b], s1 = bstart[b + 1];
    for (int i = s0 + threadIdx.x; i < s1; i += 256) atomicAdd(&lcnt[sp[i].y - base], 1);
    __syncthreads();
    for (int j = threadIdx.x; j < 1024; j += 256) {
        int n = base + j;
        if (n < N_NODES) {
            int c = lcnt[j];
            cnt[n] = c;
            dsq[n] = rsqrtf((float)c + 1.0f);
        }
    }
}

// xp2 = packed bf16 of dsq[n]*x, padded to 16 channels (8 uints / 4 uint2 per node)
__global__ void k_xprep2(const float* __restrict__ x, const float* __restrict__ dsq,
                         uint* __restrict__ xp2) {
    int i = blockIdx.x * blockDim.x + threadIdx.x;
    int stride = gridDim.x * blockDim.x;
    const int total = N_NODES * 8;
    for (; i < total; i += stride) {
        int n = i >> 3, u = i & 7;
        int c0 = 2 * u, c1 = c0 + 1;
        float d = dsq[n];
        float v0 = (c0 < 12) ? x[n * 12 + c0] * d : 0.0f;
        float v1 = (c1 < 12) ? x[n * 12 + c1] * d : 0.0f;
        xp2[i] = pack2(v0, v1);
    }
}

// exclusive scan of node counts, 3 phases
__global__ void k_scan1(const int* __restrict__ cnt, int* __restrict__ rowptr,
                        int* __restrict__ bsum, int n) {
    __shared__ int tmp[SCAN_B];
    int i = blockIdx.x * SCAN_B + threadIdx.x;
    int v = (i < n) ? cnt[i] : 0;
    tmp[threadIdx.x] = v;
    __syncthreads();
    int acc = v;
    for (int off = 1; off < SCAN_B; off <<= 1) {
        int t = (threadIdx.x >= off) ? tmp[threadIdx.x - off] : 0;
        __syncthreads();
        acc += t;
        tmp[threadIdx.x] = acc;
        __syncthreads();
    }
    if (i < n) rowptr[i] = acc - v;
    if (threadIdx.x == SCAN_B - 1) bsum[blockIdx.x] = acc;
}
__global__ void k_scan2(int* __restrict__ bsum, int nb, int* __restrict__ rowptr, int E) {
    if (blockIdx.x == 0 && threadIdx.x == 0) {
        int run = 0;
        for (int b = 0; b < nb; ++b) { int t = bsum[b]; bsum[b] = run; run += t; }
        rowptr[N_NODES] = E;
    }
}
__global__ void k_scan3(int* __restrict__ rowptr, const int* __restrict__ bsum,
                        int* __restrict__ cursor, int n) {
    int i = blockIdx.x * blockDim.x + threadIdx.x;
    int stride = gridDim.x * blockDim.x;
    for (; i < n; i += stride) {
        int v = rowptr[i] + bsum[i / SCAN_B];
        rowptr[i] = v;
        cursor[i] = v;
    }
}

// CSR scatter over bucket-ordered pairs: writes localized to ~131KB windows
__global__ void k_scatter2(const int2* __restrict__ sp, int E,
                           int* __restrict__ cursor, int* __restrict__ csr) {
    int i = blockIdx.x * blockDim.x + threadIdx.x;
    int stride = gridDim.x * blockDim.x;
    for (; i < E; i += stride) {
        int2 p = sp[i];
        int pos = atomicAdd(&cursor[p.y], 1);
        csr[pos] = p.x;
    }
}

// fused 64-dim layer: pull-aggregate bf16 rows (uint2, 4 edge-slots, 4 loads
// in flight) + 64x64 matmul + act
template <int ACT, int LAST>
__global__ __launch_bounds__(256) void k_layer64(
    const int* __restrict__ rowptr, const int* __restrict__ csr,
    const float* __restrict__ dsq, const uint2* __restrict__ hin2,
    const float* __restrict__ W, const float* __restrict__ b,
    uint* __restrict__ hout2, float* __restrict__ houtf) {
    __shared__ float Wl[64 * 64];
    __shared__ float rows[4][64];
    for (int i = threadIdx.x; i < 64 * 64; i += 256) Wl[i] = W[i];

    int wid = threadIdx.x >> 6;
    int lane = threadIdx.x & 63;
    int node = blockIdx.x * 4 + wid;
    int q = lane >> 4;       // edge slot 0..3
    int cc = lane & 15;      // uint2 index in row -> channels 4cc..4cc+3

    int start = rowptr[node], end = rowptr[node + 1];
    float dn = dsq[node];

    float a0 = 0.0f, a1 = 0.0f, a2 = 0.0f, a3 = 0.0f;
    if (q == 0) {
        uint2 u = hin2[node * 16 + cc];     // self-loop (h' already dsq-scaled)
        a0 = bflo(u.x); a1 = bfhi(u.x); a2 = bflo(u.y); a3 = bfhi(u.y);
    }

    for (int k0 = start; k0 < end; k0 += 64) {
        int idx = k0 + lane;
        int s = (idx < end) ? csr[idx] : 0;
        int nk = end - k0; if (nk > 64) nk = 64;
        for (int jj = 0; jj < nk; jj += 16) {
            int e0 = jj + q, e1 = jj + 4 + q, e2 = jj + 8 + q, e3 = jj + 12 + q;
            int s0 = __shfl(s, e0, 64);
            int s1 = __shfl(s, e1, 64);
            int s2 = __shfl(s, e2, 64);
            int s3 = __shfl(s, e3, 64);
            uint2 u0 = make_uint2(0u, 0u), u1 = make_uint2(0u, 0u);
            uint2 u2 = make_uint2(0u, 0u), u3 = make_uint2(0u, 0u);
            if (e0 < nk) u0 = hin2[s0 * 16 + cc];
            if (e1 < nk) u1 = hin2[s1 * 16 + cc];
            if (e2 < nk) u2 = hin2[s2 * 16 + cc];
            if (e3 < nk) u3 = hin2[s3 * 16 + cc];
            a0 += bflo(u0.x); a1 += bfhi(u0.x); a2 += bflo(u0.y); a3 += bfhi(u0.y);
            a0 += bflo(u1.x); a1 += bfhi(u1.x); a2 += bflo(u1.y); a3 += bfhi(u1.y);
            a0 += bflo(u2.x); a1 += bfhi(u2.x); a2 += bflo(u2.y); a3 += bfhi(u2.y);
            a0 += bflo(u3.x); a1 += bfhi(u3.x); a2 += bflo(u3.y); a3 += bfhi(u3.y);
        }
    }
    a0 += __shfl_xor(a0, 16, 64); a0 += __shfl_xor(a0, 32, 64);
    a1 += __shfl_xor(a1, 16, 64); a1 += __shfl_xor(a1, 32, 64);
    a2 += __shfl_xor(a2, 16, 64); a2 += __shfl_xor(a2, 32, 64);
    a3 += __shfl_xor(a3, 16, 64); a3 += __shfl_xor(a3, 32, 64);
    if (q == 0) {
        rows[wid][4 * cc + 0] = dn * a0;
        rows[wid][4 * cc + 1] = dn * a1;
        rows[wid][4 * cc + 2] = dn * a2;
        rows[wid][4 * cc + 3] = dn * a3;
    }
    __syncthreads();

    float sacc = b[lane];
#pragma unroll 16
    for (int k = 0; k < 64; ++k) sacc += rows[wid][k] * Wl[k * 64 + lane];
    float val = ACT ? fmaxf(sacc, 0.0f) : (sacc > 0.0f ? sacc : 0.01f * sacc);

    if (LAST) {
        houtf[node * 64 + lane] = val;
    } else {
        float sv = dn * val;
        float pv = __shfl_xor(sv, 1, 64);
        if ((lane & 1) == 0) hout2[node * 32 + (lane >> 1)] = pack2(sv, pv);
    }
}

// layer 0: pull-aggregate bf16 xp2 (16-ch padded, uint2, 16 edge-slots,
// 2 loads in flight = 32 edges/iter) + 12x64 matmul + leaky, bf16 packed out
__global__ __launch_bounds__(256) void k_layer12(
    const int* __restrict__ rowptr, const int* __restrict__ csr,
    const float* __restrict__ dsq, const uint2* __restrict__ xp2,
    const float* __restrict__ W, const float* __restrict__ b,
    uint* __restrict__ hout2) {
    __shared__ float Wl[12 * 64];
    __shared__ float rows[4][16];
    for (int i = threadIdx.x; i < 12 * 64; i += 256) Wl[i] = W[i];

    int wid = threadIdx.x >> 6;
    int lane = threadIdx.x & 63;
    int node = blockIdx.x * 4 + wid;
    int q = lane >> 2;       // edge slot 0..15
    int cc = lane & 3;       // uint2 index -> channels 4cc..4cc+3 (of 16)

    int start = rowptr[node], end = rowptr[node + 1];
    float dn = dsq[node];

    float a0 = 0.0f, a1 = 0.0f, a2 = 0.0f, a3 = 0.0f;
    if (q == 0) {
        uint2 u = xp2[node * 4 + cc];
        a0 = bflo(u.x); a1 = bfhi(u.x); a2 = bflo(u.y); a3 = bfhi(u.y);
    }

    for (int k0 = start; k0 < end; k0 += 64) {
        int idx = k0 + lane;
        int s = (idx < end) ? csr[idx] : 0;
        int nk = end - k0; if (nk > 64) nk = 64;
        for (int jj = 0; jj < nk; jj += 32) {
            int e0 = jj + q, e1 = jj + 16 + q;
            int s0 = __shfl(s, e0, 64);
            int s1 = __shfl(s, e1, 64);
            uint2 u0 = make_uint2(0u, 0u), u1 = make_uint2(0u, 0u);
            if (e0 < nk) u0 = xp2[s0 * 4 + cc];
            if (e1 < nk) u1 = xp2[s1 * 4 + cc];
            a0 += bflo(u0.x); a1 += bfhi(u0.x); a2 += bflo(u0.y); a3 += bfhi(u0.y);
            a0 += bflo(u1.x); a1 += bfhi(u1.x); a2 += bflo(u1.y); a3 += bfhi(u1.y);
        }
    }
    a0 += __shfl_xor(a0, 4, 64); a0 += __shfl_xor(a0, 8, 64);
    a0 += __shfl_xor(a0, 16, 64); a0 += __shfl_xor(a0, 32, 64);
    a1 += __shfl_xor(a1, 4, 64); a1 += __shfl_xor(a1, 8, 64);
    a1 += __shfl_xor(a1, 16, 64); a1 += __shfl_xor(a1, 32, 64);
    a2 += __shfl_xor(a2, 4, 64); a2 += __shfl_xor(a2, 8, 64);
    a2 += __shfl_xor(a2, 16, 64); a2 += __shfl_xor(a2, 32, 64);
    a3 += __shfl_xor(a3, 4, 64); a3 += __shfl_xor(a3, 8, 64);
    a3 += __shfl_xor(a3, 16, 64); a3 += __shfl_xor(a3, 32, 64);
    if (q == 0) {
        rows[wid][4 * cc + 0] = dn * a0;
        rows[wid][4 * cc + 1] = dn * a1;
        rows[wid][4 * cc + 2] = dn * a2;
        rows[wid][4 * cc + 3] = dn * a3;
    }
    __syncthreads();

    float sacc = b[lane];
#pragma unroll
    for (int k = 0; k < 12; ++k) sacc += rows[wid][k] * Wl[k * 64 + lane];
    float val = (sacc > 0.0f) ? sacc : 0.01f * sacc;
    float sv = dn * val;
    float pv = __shfl_xor(sv, 1, 64);
    if ((lane & 1) == 0) hout2[node * 32 + (lane >> 1)] = pack2(sv, pv);
}

// segmented mean-pool using sorted batch_index
__global__ void k_pool(const float* __restrict__ h, const int* __restrict__ batch,
                       float* __restrict__ psum, float* __restrict__ pcnt) {
    const int CHUNK = 256;
    int lane = threadIdx.x;
    int start = blockIdx.x * CHUNK;
    if (start >= N_NODES) return;
    int end = start + CHUNK;
    if (end > N_NODES) end = N_NODES;

    int curg = batch[start];
    float acc = 0.0f;
    int cnt = 0;
    for (int n = start; n < end; ++n) {
        int g = batch[n];
        if (g != curg) {
            atomicAdd(&psum[curg * EMB + lane], acc);
            if (lane == 0) atomicAdd(&pcnt[curg], (float)cnt);
            acc = 0.0f; cnt = 0; curg = g;
        }
        acc += h[n * EMB + lane];
        ++cnt;
    }
    atomicAdd(&psum[curg * EMB + lane], acc);
    if (lane == 0) atomicAdd(&pcnt[curg], (float)cnt);
}

__global__ void k_fc(const float* __restrict__ psum, const float* __restrict__ pcnt,
                     const float* __restrict__ Wfc, const float* __restrict__ bfc,
                     float* __restrict__ out) {
    int g = blockIdx.x;
    int lane = threadIdx.x;
    float v = psum[g * EMB + lane] * Wfc[lane];
#pragma unroll
    for (int off = 32; off; off >>= 1) v += __shfl_down(v, off, 64);
    if (lane == 0) {
        float c = fmaxf(pcnt[g], 1.0f);
        float z = v / c + bfc[0];
        out[g] = 1.0f / (1.0f + expf(-z));
    }
}

extern "C" void kernel_launch(void* const* d_in, const int* in_sizes, int n_in,
                              void* d_out, int out_size, void* d_ws, size_t ws_size,
                              hipStream_t stream) {
    const float* x     = (const float*)d_in[0];
    const int*   edge  = (const int*)d_in[1];
    const int*   batch = (const int*)d_in[2];
    const float* W0 = (const float*)d_in[3];
    const float* b0 = (const float*)d_in[4];
    const float* W1 = (const float*)d_in[5];
    const float* b1 = (const float*)d_in[6];
    const float* W2 = (const float*)d_in[7];
    const float* b2 = (const float*)d_in[8];
    const float* W3 = (const float*)d_in[9];
    const float* b3 = (const float*)d_in[10];
    const float* Wfc = (const float*)d_in[11];
    const float* bfc = (const float*)d_in[12];
    float* out = (float*)d_out;

    const int E = in_sizes[1] / 2;
    const int* src = edge;
    const int* dst = edge + E;

    // workspace layout
    char* ws = (char*)d_ws;
    float* dsq    = (float*)ws;                   ws += sizeof(float) * N_NODES;
    int*   cnt    = (int*)ws;                     ws += sizeof(int) * N_NODES;
    int*   rowptr = (int*)ws;                     ws += sizeof(int) * (N_NODES + 1);
    int*   cursor = (int*)ws;                     ws += sizeof(int) * N_NODES;
    int*   bsum   = (int*)ws;                     ws += sizeof(int) * 128;
    int*   bcnt   = (int*)ws;                     ws += sizeof(int) * 128;
    int*   bstart = (int*)ws;                     ws += sizeof(int) * 128;
    int*   bcursor= (int*)ws;                     ws += sizeof(int) * 128;
    ws = (char*)(((size_t)ws + 15) & ~(size_t)15);
    uint*  xp2    = (uint*)ws;                    ws += sizeof(uint) * N_NODES * 8;
    int*   csr    = (int*)ws;                     ws += sizeof(int) * E;
    uint*  bufA   = (uint*)ws;                    ws += sizeof(uint) * N_NODES * 32;
    uint*  bufB   = (uint*)ws;                    ws += sizeof(uint) * N_NODES * 32;
    float* bufF   = (float*)ws;                   ws += sizeof(float) * N_NODES * EMB;
    float* psum   = (float*)ws;                   ws += sizeof(float) * N_GRAPHS * EMB;
    float* pcnt   = (float*)ws;
    int2*  sp     = (int2*)bufA;   // sorted pairs alias bufA+bufB (dead until layer 0)

    const int NB = (N_NODES + SCAN_B - 1) / SCAN_B;   // 98

    // ---- bucket sort + per-node counts + rowptr ----
    k_zero_i<<<1, 128, 0, stream>>>(bcnt, 128);
    k_bhist<<<512, 256, 0, stream>>>(dst, E, bcnt);
    k_bscan<<<1, 64, 0, stream>>>(bcnt, bstart, bcursor);
    k_bscatter<<<(E + CHUNK_E - 1) / CHUNK_E, 256, 0, stream>>>(src, dst, E, bcursor, sp);
    k_cnt2<<<NBKT, 256, 0, stream>>>(sp, bstart, cnt, dsq);
    k_xprep2<<<512, 256, 0, stream>>>(x, dsq, xp2);
    k_scan1<<<NB, SCAN_B, 0, stream>>>(cnt, rowptr, bsum, N_NODES);
    k_scan2<<<1, 64, 0, stream>>>(bsum, NB, rowptr, E);
    k_scan3<<<256, 256, 0, stream>>>(rowptr, bsum, cursor, N_NODES);
    k_scatter2<<<2048, 256, 0, stream>>>(sp, E, cursor, csr);

    // ---- 4 fused GCN layers ----
    const int NBLK = N_NODES / 4;   // 25000, exact
    k_layer12<<<NBLK, 256, 0, stream>>>(rowptr, csr, dsq, (const uint2*)xp2, W0, b0, bufA);
    k_layer64<0, 0><<<NBLK, 256, 0, stream>>>(rowptr, csr, dsq, (const uint2*)bufA, W1, b1, bufB, nullptr);
    k_layer64<0, 0><<<NBLK, 256, 0, stream>>>(rowptr, csr, dsq, (const uint2*)bufB, W2, b2, bufA, nullptr);
    k_layer64<1, 1><<<NBLK, 256, 0, stream>>>(rowptr, csr, dsq, (const uint2*)bufA, W3, b3, nullptr, bufF);

    // ---- mean pool + fc + sigmoid ----
    k_zero_f<<<64, 256, 0, stream>>>(psum, N_GRAPHS * EMB + N_GRAPHS);
    k_pool<<<(N_NODES + 255) / 256, 64, 0, stream>>>(bufF, batch, psum, pcnt);
    k_fc<<<N_GRAPHS, 64, 0, stream>>>(psum, pcnt, Wfc, bfc, out);
}

// Round 6
// 610.228 us; speedup vs baseline: 4.3915x; 1.1067x over previous
//
#include <hip/hip_runtime.h>
#include <math.h>

#define N_NODES 100000
#define N_GRAPHS 512
#define EMB 64
#define SCAN_B 1024
#define NBKT 98          // ceil(100000 / 1024) buckets of 1024 nodes
#define CHUNK_E 4096     // edges per k_bscatter block

typedef unsigned int uint;

// ---------------- bf16 pack/unpack ----------------
__device__ __forceinline__ float bflo(uint u) { return __uint_as_float(u << 16); }
__device__ __forceinline__ float bfhi(uint u) { return __uint_as_float(u & 0xffff0000u); }
__device__ __forceinline__ uint rne16(float f) {
    uint u = __float_as_uint(f);
    return (u + 0x7fffu + ((u >> 16) & 1u)) >> 16;
}
__device__ __forceinline__ uint pack2(float a, float b) {
    return rne16(a) | (rne16(b) << 16);
}

// ---------------- utility ----------------
__global__ void k_zero_f(float* __restrict__ p, int n) {
    int i = blockIdx.x * blockDim.x + threadIdx.x;
    int stride = gridDim.x * blockDim.x;
    for (; i < n; i += stride) p[i] = 0.0f;
}
__global__ void k_zero_i(int* __restrict__ p, int n) {
    int i = blockIdx.x * blockDim.x + threadIdx.x;
    int stride = gridDim.x * blockDim.x;
    for (; i < n; i += stride) p[i] = 0;
}

// bucket histogram of dst>>10, LDS-staged
__global__ __launch_bounds__(256) void k_bhist(const int* __restrict__ dst, int E,
                                               int* __restrict__ bcnt) {
    __shared__ int w[NBKT];
    for (int i = threadIdx.x; i < NBKT; i += 256) w[i] = 0;
    __syncthreads();
    int i = blockIdx.x * 256 + threadIdx.x;
    int stride = gridDim.x * 256;
    for (; i < E; i += stride) atomicAdd(&w[dst[i] >> 10], 1);
    __syncthreads();
    for (int t = threadIdx.x; t < NBKT; t += 256)
        if (w[t]) atomicAdd(&bcnt[t], w[t]);
}

__global__ void k_bscan(const int* __restrict__ bcnt, int* __restrict__ bstart,
                        int* __restrict__ bcursor) {
    if (blockIdx.x == 0 && threadIdx.x == 0) {
        int run = 0;
        for (int b = 0; b < NBKT; ++b) { bstart[b] = run; bcursor[b] = run; run += bcnt[b]; }
        bstart[NBKT] = run;
    }
}

// counting-sort pass: partition edges into dst-buckets with LDS staging so
// global writes are coalesced per-bucket runs. sp[pos] = (src, dst).
__global__ __launch_bounds__(256) void k_bscatter(
    const int* __restrict__ src, const int* __restrict__ dst, int E,
    int* __restrict__ bcursor, int2* __restrict__ sp) {
    __shared__ int wcnt[NBKT];
    __shared__ int wbase[NBKT];
    __shared__ int lofs[NBKT];
    __shared__ int lcur[NBKT];
    __shared__ int2 stage[CHUNK_E];
    __shared__ short sbkt[CHUNK_E];

    int e0 = blockIdx.x * CHUNK_E;
    int e1 = e0 + CHUNK_E;
    if (e1 > E) e1 = E;
    int t = threadIdx.x;

    for (int i = t; i < NBKT; i += 256) { wcnt[i] = 0; lcur[i] = 0; }
    __syncthreads();
    for (int i = e0 + t; i < e1; i += 256) atomicAdd(&wcnt[dst[i] >> 10], 1);
    __syncthreads();
    if (t < NBKT) wbase[t] = atomicAdd(&bcursor[t], wcnt[t]);
    if (t == 0) {
        int run = 0;
        for (int b = 0; b < NBKT; ++b) { lofs[b] = run; run += wcnt[b]; }
    }
    __syncthreads();
    for (int i = e0 + t; i < e1; i += 256) {
        int d = dst[i];
        int b = d >> 10;
        int l = lofs[b] + atomicAdd(&lcur[b], 1);
        stage[l] = make_int2(src[i], d);
        sbkt[l] = (short)b;
    }
    __syncthreads();
    int n = e1 - e0;
    for (int k = t; k < n; k += 256) {
        int b = sbkt[k];
        sp[wbase[b] + (k - lofs[b])] = stage[k];
    }
}

// per-node counts + dsq from bucket-sorted pairs (one block per bucket)
__global__ __launch_bounds__(256) void k_cnt2(const int2* __restrict__ sp,
                                              const int* __restrict__ bstart,
                                              int* __restrict__ cnt,
                                              float* __restrict__ dsq) {
    __shared__ int lcnt[1024];
    int b = blockIdx.x;
    int base = b << 10;
    for (int j = threadIdx.x; j < 1024; j += 256) lcnt[j] = 0;
    __syncthreads();
    int s0 = bstart[b], s1 = bstart[b + 1];
    for (int i = s0 + threadIdx.x; i < s1; i += 256) atomicAdd(&lcnt[sp[i].y - base], 1);
    __syncthreads();
    for (int j = threadIdx.x; j < 1024; j += 256) {
        int n = base + j;
        if (n < N_NODES) {
            int c = lcnt[j];
            cnt[n] = c;
            dsq[n] = rsqrtf((float)c + 1.0f);
        }
    }
}

// xp2 = packed bf16 of dsq[n]*x, padded to 16 channels (8 uints / 4 uint2 per node)
__global__ void k_xprep2(const float* __restrict__ x, const float* __restrict__ dsq,
                         uint* __restrict__ xp2) {
    int i = blockIdx.x * blockDim.x + threadIdx.x;
    int stride = gridDim.x * blockDim.x;
    const int total = N_NODES * 8;
    for (; i < total; i += stride) {
        int n = i >> 3, u = i & 7;
        int c0 = 2 * u, c1 = c0 + 1;
        float d = dsq[n];
        float v0 = (c0 < 12) ? x[n * 12 + c0] * d : 0.0f;
        float v1 = (c1 < 12) ? x[n * 12 + c1] * d : 0.0f;
        xp2[i] = pack2(v0, v1);
    }
}

// exclusive scan of node counts, 3 phases
__global__ void k_scan1(const int* __restrict__ cnt, int* __restrict__ rowptr,
                        int* __restrict__ bsum, int n) {
    __shared__ int tmp[SCAN_B];
    int i = blockIdx.x * SCAN_B + threadIdx.x;
    int v = (i < n) ? cnt[i] : 0;
    tmp[threadIdx.x] = v;
    __syncthreads();
    int acc = v;
    for (int off = 1; off < SCAN_B; off <<= 1) {
        int t = (threadIdx.x >= off) ? tmp[threadIdx.x - off] : 0;
        __syncthreads();
        acc += t;
        tmp[threadIdx.x] = acc;
        __syncthreads();
    }
    if (i < n) rowptr[i] = acc - v;
    if (threadIdx.x == SCAN_B - 1) bsum[blockIdx.x] = acc;
}
__global__ void k_scan2(int* __restrict__ bsum, int nb, int* __restrict__ rowptr, int E) {
    if (blockIdx.x == 0 && threadIdx.x == 0) {
        int run = 0;
        for (int b = 0; b < nb; ++b) { int t = bsum[b]; bsum[b] = run; run += t; }
        rowptr[N_NODES] = E;
    }
}
__global__ void k_scan3(int* __restrict__ rowptr, const int* __restrict__ bsum, int n) {
    int i = blockIdx.x * blockDim.x + threadIdx.x;
    int stride = gridDim.x * blockDim.x;
    for (; i < n; i += stride) rowptr[i] += bsum[i / SCAN_B];
}

// CSR scatter, one block per bucket: LDS cursors from rowptr, writes stay in
// this block's ~131KB csr window (single-XCD L2 resident, evicted once)
__global__ __launch_bounds__(256) void k_scatter3(const int2* __restrict__ sp,
                                                  const int* __restrict__ bstart,
                                                  const int* __restrict__ rowptr,
                                                  int* __restrict__ csr) {
    __shared__ int lcur[1024];
    int b = blockIdx.x;
    int base = b << 10;
    for (int j = threadIdx.x; j < 1024; j += 256) {
        int n = base + j;
        lcur[j] = (n < N_NODES) ? rowptr[n] : 0;
    }
    __syncthreads();
    int s0 = bstart[b], s1 = bstart[b + 1];
    for (int i = s0 + threadIdx.x; i < s1; i += 256) {
        int2 p = sp[i];
        int pos = atomicAdd(&lcur[p.y - base], 1);
        csr[pos] = p.x;
    }
}

// fused 64-dim layer: pull-aggregate bf16 rows (uint2, 4 edge-slots, 4 loads
// in flight) + 64x64 matmul + act
template <int ACT, int LAST>
__global__ __launch_bounds__(256) void k_layer64(
    const int* __restrict__ rowptr, const int* __restrict__ csr,
    const float* __restrict__ dsq, const uint2* __restrict__ hin2,
    const float* __restrict__ W, const float* __restrict__ b,
    uint* __restrict__ hout2, float* __restrict__ houtf) {
    __shared__ float Wl[64 * 64];
    __shared__ float rows[4][64];
    for (int i = threadIdx.x; i < 64 * 64; i += 256) Wl[i] = W[i];

    int wid = threadIdx.x >> 6;
    int lane = threadIdx.x & 63;
    int node = blockIdx.x * 4 + wid;
    int q = lane >> 4;       // edge slot 0..3
    int cc = lane & 15;      // uint2 index in row -> channels 4cc..4cc+3

    int start = rowptr[node], end = rowptr[node + 1];
    float dn = dsq[node];

    float a0 = 0.0f, a1 = 0.0f, a2 = 0.0f, a3 = 0.0f;
    if (q == 0) {
        uint2 u = hin2[node * 16 + cc];     // self-loop (h' already dsq-scaled)
        a0 = bflo(u.x); a1 = bfhi(u.x); a2 = bflo(u.y); a3 = bfhi(u.y);
    }

    for (int k0 = start; k0 < end; k0 += 64) {
        int idx = k0 + lane;
        int s = (idx < end) ? csr[idx] : 0;
        int nk = end - k0; if (nk > 64) nk = 64;
        for (int jj = 0; jj < nk; jj += 16) {
            int e0 = jj + q, e1 = jj + 4 + q, e2 = jj + 8 + q, e3 = jj + 12 + q;
            int s0 = __shfl(s, e0, 64);
            int s1 = __shfl(s, e1, 64);
            int s2 = __shfl(s, e2, 64);
            int s3 = __shfl(s, e3, 64);
            uint2 u0 = make_uint2(0u, 0u), u1 = make_uint2(0u, 0u);
            uint2 u2 = make_uint2(0u, 0u), u3 = make_uint2(0u, 0u);
            if (e0 < nk) u0 = hin2[s0 * 16 + cc];
            if (e1 < nk) u1 = hin2[s1 * 16 + cc];
            if (e2 < nk) u2 = hin2[s2 * 16 + cc];
            if (e3 < nk) u3 = hin2[s3 * 16 + cc];
            a0 += bflo(u0.x); a1 += bfhi(u0.x); a2 += bflo(u0.y); a3 += bfhi(u0.y);
            a0 += bflo(u1.x); a1 += bfhi(u1.x); a2 += bflo(u1.y); a3 += bfhi(u1.y);
            a0 += bflo(u2.x); a1 += bfhi(u2.x); a2 += bflo(u2.y); a3 += bfhi(u2.y);
            a0 += bflo(u3.x); a1 += bfhi(u3.x); a2 += bflo(u3.y); a3 += bfhi(u3.y);
        }
    }
    a0 += __shfl_xor(a0, 16, 64); a0 += __shfl_xor(a0, 32, 64);
    a1 += __shfl_xor(a1, 16, 64); a1 += __shfl_xor(a1, 32, 64);
    a2 += __shfl_xor(a2, 16, 64); a2 += __shfl_xor(a2, 32, 64);
    a3 += __shfl_xor(a3, 16, 64); a3 += __shfl_xor(a3, 32, 64);
    if (q == 0) {
        rows[wid][4 * cc + 0] = dn * a0;
        rows[wid][4 * cc + 1] = dn * a1;
        rows[wid][4 * cc + 2] = dn * a2;
        rows[wid][4 * cc + 3] = dn * a3;
    }
    __syncthreads();

    float sacc = b[lane];
#pragma unroll 16
    for (int k = 0; k < 64; ++k) sacc += rows[wid][k] * Wl[k * 64 + lane];
    float val = ACT ? fmaxf(sacc, 0.0f) : (sacc > 0.0f ? sacc : 0.01f * sacc);

    if (LAST) {
        houtf[node * 64 + lane] = val;
    } else {
        float sv = dn * val;
        float pv = __shfl_xor(sv, 1, 64);
        if ((lane & 1) == 0) hout2[node * 32 + (lane >> 1)] = pack2(sv, pv);
    }
}

// layer 0: pull-aggregate bf16 xp2 (16-ch padded, uint2, 16 edge-slots,
// 2 loads in flight = 32 edges/iter) + 12x64 matmul + leaky, bf16 packed out
__global__ __launch_bounds__(256) void k_layer12(
    const int* __restrict__ rowptr, const int* __restrict__ csr,
    const float* __restrict__ dsq, const uint2* __restrict__ xp2,
    const float* __restrict__ W, const float* __restrict__ b,
    uint* __restrict__ hout2) {
    __shared__ float Wl[12 * 64];
    __shared__ float rows[4][16];
    for (int i = threadIdx.x; i < 12 * 64; i += 256) Wl[i] = W[i];

    int wid = threadIdx.x >> 6;
    int lane = threadIdx.x & 63;
    int node = blockIdx.x * 4 + wid;
    int q = lane >> 2;       // edge slot 0..15
    int cc = lane & 3;       // uint2 index -> channels 4cc..4cc+3 (of 16)

    int start = rowptr[node], end = rowptr[node + 1];
    float dn = dsq[node];

    float a0 = 0.0f, a1 = 0.0f, a2 = 0.0f, a3 = 0.0f;
    if (q == 0) {
        uint2 u = xp2[node * 4 + cc];
        a0 = bflo(u.x); a1 = bfhi(u.x); a2 = bflo(u.y); a3 = bfhi(u.y);
    }

    for (int k0 = start; k0 < end; k0 += 64) {
        int idx = k0 + lane;
        int s = (idx < end) ? csr[idx] : 0;
        int nk = end - k0; if (nk > 64) nk = 64;
        for (int jj = 0; jj < nk; jj += 32) {
            int e0 = jj + q, e1 = jj + 16 + q;
            int s0 = __shfl(s, e0, 64);
            int s1 = __shfl(s, e1, 64);
            uint2 u0 = make_uint2(0u, 0u), u1 = make_uint2(0u, 0u);
            if (e0 < nk) u0 = xp2[s0 * 4 + cc];
            if (e1 < nk) u1 = xp2[s1 * 4 + cc];
            a0 += bflo(u0.x); a1 += bfhi(u0.x); a2 += bflo(u0.y); a3 += bfhi(u0.y);
            a0 += bflo(u1.x); a1 += bfhi(u1.x); a2 += bflo(u1.y); a3 += bfhi(u1.y);
        }
    }
    a0 += __shfl_xor(a0, 4, 64); a0 += __shfl_xor(a0, 8, 64);
    a0 += __shfl_xor(a0, 16, 64); a0 += __shfl_xor(a0, 32, 64);
    a1 += __shfl_xor(a1, 4, 64); a1 += __shfl_xor(a1, 8, 64);
    a1 += __shfl_xor(a1, 16, 64); a1 += __shfl_xor(a1, 32, 64);
    a2 += __shfl_xor(a2, 4, 64); a2 += __shfl_xor(a2, 8, 64);
    a2 += __shfl_xor(a2, 16, 64); a2 += __shfl_xor(a2, 32, 64);
    a3 += __shfl_xor(a3, 4, 64); a3 += __shfl_xor(a3, 8, 64);
    a3 += __shfl_xor(a3, 16, 64); a3 += __shfl_xor(a3, 32, 64);
    if (q == 0) {
        rows[wid][4 * cc + 0] = dn * a0;
        rows[wid][4 * cc + 1] = dn * a1;
        rows[wid][4 * cc + 2] = dn * a2;
        rows[wid][4 * cc + 3] = dn * a3;
    }
    __syncthreads();

    float sacc = b[lane];
#pragma unroll
    for (int k = 0; k < 12; ++k) sacc += rows[wid][k] * Wl[k * 64 + lane];
    float val = (sacc > 0.0f) ? sacc : 0.01f * sacc;
    float sv = dn * val;
    float pv = __shfl_xor(sv, 1, 64);
    if ((lane & 1) == 0) hout2[node * 32 + (lane >> 1)] = pack2(sv, pv);
}

// segmented mean-pool using sorted batch_index
__global__ void k_pool(const float* __restrict__ h, const int* __restrict__ batch,
                       float* __restrict__ psum, float* __restrict__ pcnt) {
    const int CHUNK = 256;
    int lane = threadIdx.x;
    int start = blockIdx.x * CHUNK;
    if (start >= N_NODES) return;
    int end = start + CHUNK;
    if (end > N_NODES) end = N_NODES;

    int curg = batch[start];
    float acc = 0.0f;
    int cnt = 0;
    for (int n = start; n < end; ++n) {
        int g = batch[n];
        if (g != curg) {
            atomicAdd(&psum[curg * EMB + lane], acc);
            if (lane == 0) atomicAdd(&pcnt[curg], (float)cnt);
            acc = 0.0f; cnt = 0; curg = g;
        }
        acc += h[n * EMB + lane];
        ++cnt;
    }
    atomicAdd(&psum[curg * EMB + lane], acc);
    if (lane == 0) atomicAdd(&pcnt[curg], (float)cnt);
}

__global__ void k_fc(const float* __restrict__ psum, const float* __restrict__ pcnt,
                     const float* __restrict__ Wfc, const float* __restrict__ bfc,
                     float* __restrict__ out) {
    int g = blockIdx.x;
    int lane = threadIdx.x;
    float v = psum[g * EMB + lane] * Wfc[lane];
#pragma unroll
    for (int off = 32; off; off >>= 1) v += __shfl_down(v, off, 64);
    if (lane == 0) {
        float c = fmaxf(pcnt[g], 1.0f);
        float z = v / c + bfc[0];
        out[g] = 1.0f / (1.0f + expf(-z));
    }
}

extern "C" void kernel_launch(void* const* d_in, const int* in_sizes, int n_in,
                              void* d_out, int out_size, void* d_ws, size_t ws_size,
                              hipStream_t stream) {
    const float* x     = (const float*)d_in[0];
    const int*   edge  = (const int*)d_in[1];
    const int*   batch = (const int*)d_in[2];
    const float* W0 = (const float*)d_in[3];
    const float* b0 = (const float*)d_in[4];
    const float* W1 = (const float*)d_in[5];
    const float* b1 = (const float*)d_in[6];
    const float* W2 = (const float*)d_in[7];
    const float* b2 = (const float*)d_in[8];
    const float* W3 = (const float*)d_in[9];
    const float* b3 = (const float*)d_in[10];
    const float* Wfc = (const float*)d_in[11];
    const float* bfc = (const float*)d_in[12];
    float* out = (float*)d_out;

    const int E = in_sizes[1] / 2;
    const int* src = edge;
    const int* dst = edge + E;

    // workspace layout
    char* ws = (char*)d_ws;
    float* dsq    = (float*)ws;                   ws += sizeof(float) * N_NODES;
    int*   cnt    = (int*)ws;                     ws += sizeof(int) * N_NODES;
    int*   rowptr = (int*)ws;                     ws += sizeof(int) * (N_NODES + 1);
    int*   bsum   = (int*)ws;                     ws += sizeof(int) * 128;
    int*   bcnt   = (int*)ws;                     ws += sizeof(int) * 128;
    int*   bstart = (int*)ws;                     ws += sizeof(int) * 128;
    int*   bcursor= (int*)ws;                     ws += sizeof(int) * 128;
    ws = (char*)(((size_t)ws + 15) & ~(size_t)15);
    uint*  xp2    = (uint*)ws;                    ws += sizeof(uint) * N_NODES * 8;
    int*   csr    = (int*)ws;                     ws += sizeof(int) * E;
    uint*  bufA   = (uint*)ws;                    ws += sizeof(uint) * N_NODES * 32;
    uint*  bufB   = (uint*)ws;                    ws += sizeof(uint) * N_NODES * 32;
    float* bufF   = (float*)ws;                   ws += sizeof(float) * N_NODES * EMB;
    float* psum   = (float*)ws;                   ws += sizeof(float) * N_GRAPHS * EMB;
    float* pcnt   = (float*)ws;
    int2*  sp     = (int2*)bufA;   // sorted pairs alias bufA+bufB (dead until layer 0)

    const int NB = (N_NODES + SCAN_B - 1) / SCAN_B;   // 98

    // ---- bucket sort + per-node counts + rowptr ----
    k_zero_i<<<1, 128, 0, stream>>>(bcnt, 128);
    k_bhist<<<512, 256, 0, stream>>>(dst, E, bcnt);
    k_bscan<<<1, 64, 0, stream>>>(bcnt, bstart, bcursor);
    k_bscatter<<<(E + CHUNK_E - 1) / CHUNK_E, 256, 0, stream>>>(src, dst, E, bcursor, sp);
    k_cnt2<<<NBKT, 256, 0, stream>>>(sp, bstart, cnt, dsq);
    k_xprep2<<<512, 256, 0, stream>>>(x, dsq, xp2);
    k_scan1<<<NB, SCAN_B, 0, stream>>>(cnt, rowptr, bsum, N_NODES);
    k_scan2<<<1, 64, 0, stream>>>(bsum, NB, rowptr, E);
    k_scan3<<<256, 256, 0, stream>>>(rowptr, bsum, N_NODES);
    k_scatter3<<<NBKT, 256, 0, stream>>>(sp, bstart, rowptr, csr);

    // ---- 4 fused GCN layers ----
    const int NBLK = N_NODES / 4;   // 25000, exact
    k_layer12<<<NBLK, 256, 0, stream>>>(rowptr, csr, dsq, (const uint2*)xp2, W0, b0, bufA);
    k_layer64<0, 0><<<NBLK, 256, 0, stream>>>(rowptr, csr, dsq, (const uint2*)bufA, W1, b1, bufB, nullptr);
    k_layer64<0, 0><<<NBLK, 256, 0, stream>>>(rowptr, csr, dsq, (const uint2*)bufB, W2, b2, bufA, nullptr);
    k_layer64<1, 1><<<NBLK, 256, 0, stream>>>(rowptr, csr, dsq, (const uint2*)bufA, W3, b3, nullptr, bufF);

    // ---- mean pool + fc + sigmoid ----
    k_zero_f<<<64, 256, 0, stream>>>(psum, N_GRAPHS * EMB + N_GRAPHS);
    k_pool<<<(N_NODES + 255) / 256, 64, 0, stream>>>(bufF, batch, psum, pcnt);
    k_fc<<<N_GRAPHS, 64, 0, stream>>>(psum, pcnt, Wfc, bfc, out);
}